// Round 14
// baseline (79.033 us; speedup 1.0000x reference)
//
#include <hip/hip_runtime.h>

typedef unsigned short ushort_t;
typedef __bf16 bf16x8 __attribute__((ext_vector_type(8)));
typedef float f32x4 __attribute__((ext_vector_type(4)));

#define AS1 __attribute__((address_space(1)))
#define AS3 __attribute__((address_space(3)))

__device__ __forceinline__ ushort_t f2bf(float f) {
    unsigned u = __builtin_bit_cast(unsigned, f);
    u = (u + 0x7fffu + ((u >> 16) & 1u)) >> 16;
    return (ushort_t)u;
}

__device__ __forceinline__ void async16(void* lds, const void* g) {
    __builtin_amdgcn_global_load_lds((const AS1 unsigned int*)g,
                                     (AS3 unsigned int*)lds, 16, 0, 0);
}

__device__ __forceinline__ void softmax2(const float* __restrict__ sig, float& s0, float& s1) {
    float a = sig[0], b = sig[1];
    float m = fmaxf(a, b);
    float e0 = __expf(a - m), e1 = __expf(b - m);
    float inv = 1.0f / (e0 + e1);
    s0 = e0 * inv; s1 = e1 * inv;
}

// toeplitz value: W_toep[k][o]
__device__ __forceinline__ float toep_val(const float* __restrict__ Wseed, int k, int o) {
    return (k >= o) ? Wseed[(size_t)(k - o) << 10] : Wseed[o - k];
}

// ---------------- prep: W_core^T bf16 (x consumed fp32 by GEMM) ----------------
__global__ __launch_bounds__(256) void prep_w_kernel(const float* __restrict__ Wseed,
                                                     const float* __restrict__ Wsig,
                                                     ushort_t* __restrict__ Wt) {
    __shared__ float T[64][65];
    int bb = blockIdx.x;                        // 0..255
    int k0 = (bb >> 4) * 64;
    int o0 = (bb & 15) * 64;
    int t = threadIdx.x;
    #pragma unroll
    for (int i = 0; i < 4; ++i) {
        int lin = t + i * 256;
        int kr = lin >> 4;
        int c4 = lin & 15;
        float4 v = *(const float4*)&Wseed[(size_t)(k0 + kr) * 1024 + o0 + c4 * 4];
        T[kr][c4 * 4 + 0] = v.x;
        T[kr][c4 * 4 + 1] = v.y;
        T[kr][c4 * 4 + 2] = v.z;
        T[kr][c4 * 4 + 3] = v.w;
    }
    __syncthreads();
    float s0, s1; softmax2(Wsig, s0, s1);
    #pragma unroll
    for (int i = 0; i < 2; ++i) {
        int lin = t + i * 256;
        int oo = lin >> 3;
        int kq = (lin & 7) * 8;
        unsigned r[4];
        #pragma unroll
        for (int q = 0; q < 4; ++q) {
            float v0 = s0 * T[kq + 2 * q + 0][oo] + s1 * toep_val(Wseed, k0 + kq + 2 * q + 0, o0 + oo);
            float v1 = s0 * T[kq + 2 * q + 1][oo] + s1 * toep_val(Wseed, k0 + kq + 2 * q + 1, o0 + oo);
            r[q] = (unsigned)f2bf(v0) | ((unsigned)f2bf(v1) << 16);
        }
        *(uint4*)&Wt[(size_t)(o0 + oo) * 1024 + k0 + kq] = make_uint4(r[0], r[1], r[2], r[3]);
    }
}

// ---------------- main GEMM: A global->register, B-only LDS, 1 barrier/step ------
// 128x128 tile, BK=32, 512 threads = 8 waves (4Mx2N, per-wave 32x64), grid 512 =
// 2 blocks/CU. LDS = 3 x 8KB B-buffers ONLY (24 KB). Per step:
//   LOADA(t+1) 4x global_load_dwordx4 -> regs (fp32 x, cvt in-reg at use)
//   s_waitcnt vmcnt(5)   [retires exactly B(t) + A(t)x4 per issue-order ledger]
//   s_barrier            [publishes B(t)]
//   STAGEB(t+2) -> buf[(t+2)%3]  (post-barrier: target last read at step t-1)
//   cvt af(t) + 8 MFMA from B-LDS
// LDS traffic/block-step: 40 KB (vs 88 KB in R13) — the R4-R13 invariant limiter.
// A-reg path differs from failed R5/R10: regs feed MFMA one step+barrier later,
// no load->ds_write->barrier chain. B staging byte-identical to R13 (passed).
#define BM 128
#define BN 128
#define BK 32
#define NKT 32   // 1024 / 32

__global__ __launch_bounds__(512, 4) void gemm_kernel(const float* __restrict__ Xf,
                                                      const ushort_t* __restrict__ Wt,
                                                      const float* __restrict__ bseed,
                                                      const float* __restrict__ bsig,
                                                      const float* __restrict__ asig,
                                                      float* __restrict__ out) {
    __shared__ ushort_t lds[12288];   // 3 x 4096 ushorts (8KB) B buffers
    ushort_t* b0 = lds;
    ushort_t* b1 = lds + 4096;
    ushort_t* b2 = lds + 8192;

    const int t = threadIdx.x;        // 0..511
    const int wv = t >> 6;            // 0..7
    const int lane = t & 63;

    // XCD-aware swizzle (512 blocks, bijective)
    const int orig = blockIdx.x;
    const int g = orig & 7;
    const int within = orig >> 3;           // 0..63
    const int rb = g * 8 + (within >> 3);   // row-block 0..63
    const int cb = within & 7;              // col-block 0..7
    const int brow = rb * BM;
    const int bcol = cb * BN;

    // ---- B staging map (R13-verified): 4 threads per 64B row, chunk ^ (row>>1)&3
    const int rbb = t >> 2;                       // 0..127
    const int cbk = (t & 3) ^ ((rbb >> 1) & 3);   // inverse-swizzled 16B chunk
    const ushort_t* gBsw = Wt + (size_t)(bcol + rbb) * 1024 + 8 * cbk;

    // fragment geometry: wave = 32 rows x 64 cols (4 M-groups x 2 N-groups)
    const int wr = (wv >> 1) * 32;     // 0,32,64,96
    const int wcn = (wv & 1) * 64;     // 0,64
    const int fr = lane & 15;
    const int kg = (lane >> 4) * 8;    // k-offset (elements)

    // ---- A fragment global base: lane reads rows (brow+wr+fr, +16), k kg..kg+7
    const float* gAw = Xf + (size_t)(brow + wr + fr) * 1024 + kg;

    f32x4 acc[2][4];
    #pragma unroll
    for (int i = 0; i < 2; ++i)
        #pragma unroll
        for (int j = 0; j < 4; ++j) acc[i][j] = (f32x4){0.f, 0.f, 0.f, 0.f};

    // epilogue scalars precomputed + pinned (keeps vmcnt ledger clean)
    float bs0, bs1, as0, as1;
    softmax2(bsig, bs0, bs1);
    softmax2(asig, as0, as1);
    float bias[4];
    #pragma unroll
    for (int ni = 0; ni < 4; ++ni)
        bias[ni] = bs0 * bseed[bcol + wcn + ni * 16 + fr];
    asm volatile("" :: "v"(bias[0]), "v"(bias[1]), "v"(bias[2]), "v"(bias[3]),
                       "v"(as0), "v"(as1));
    asm volatile("" ::: "memory");

    // A staging registers, two named sets (static indexing, rule #20)
    f32x4 aE0, aE1, aE2, aE3, aO0, aO1, aO2, aO3;

#define LOADA(r0_, r1_, r2_, r3_, ko)                              \
    do {                                                           \
        r0_ = *(const f32x4*)(gAw + (ko));                         \
        r1_ = *(const f32x4*)(gAw + (ko) + 4);                     \
        r2_ = *(const f32x4*)(gAw + 16384 + (ko));                 \
        r3_ = *(const f32x4*)(gAw + 16384 + (ko) + 4);             \
    } while (0)

#define STAGEB(buf, ko) async16((buf) + wv * 512, gBsw + (ko))

#define COMPUTE(r0_, r1_, r2_, r3_, Bbuf)                                          \
    do {                                                                           \
        bf16x8 af0, af1, bf[4];                                                    \
        _Pragma("unroll")                                                          \
        for (int j_ = 0; j_ < 4; ++j_) {                                           \
            af0[j_]     = (__bf16)r0_[j_];                                         \
            af0[4 + j_] = (__bf16)r1_[j_];                                         \
            af1[j_]     = (__bf16)r2_[j_];                                         \
            af1[4 + j_] = (__bf16)r3_[j_];                                         \
        }                                                                          \
        _Pragma("unroll")                                                          \
        for (int ni = 0; ni < 4; ++ni) {                                           \
            int rb_ = wcn + ni * 16 + fr;                                          \
            int ch_ = ((kg >> 3) ^ ((rb_ >> 1) & 3)) << 3;                         \
            bf[ni] = *(const bf16x8*)&(Bbuf)[rb_ * 32 + ch_];                      \
        }                                                                          \
        _Pragma("unroll")                                                          \
        for (int ni = 0; ni < 4; ++ni) {                                           \
            acc[0][ni] = __builtin_amdgcn_mfma_f32_16x16x32_bf16(af0, bf[ni],      \
                                                                 acc[0][ni], 0, 0, 0); \
            acc[1][ni] = __builtin_amdgcn_mfma_f32_16x16x32_bf16(af1, bf[ni],      \
                                                                 acc[1][ni], 0, 0, 0); \
        }                                                                          \
    } while (0)

#define WAIT5() asm volatile("s_waitcnt vmcnt(5)" ::: "memory")
#define WAIT0() asm volatile("s_waitcnt vmcnt(0)" ::: "memory")
#define BAR()   __builtin_amdgcn_s_barrier()

    // prologue: A(0)->regs, B(0)->b0, B(1)->b1; retire A(0)+B(0) (vmcnt(1))
    LOADA(aE0, aE1, aE2, aE3, 0);
    STAGEB(b0, 0);
    STAGEB(b1, 32);
    asm volatile("s_waitcnt vmcnt(1)" ::: "memory");
    BAR();

    // main: 15 double-steps (T = 0..29)
    for (int i = 0; i < 15; ++i) {
        const int T = 2 * i;
        // even step T: compute aE/b0, load A(T+1) into aO, stage B(T+2)->b2
        LOADA(aO0, aO1, aO2, aO3, (size_t)(T + 1) * 32);
        WAIT5(); BAR();
        STAGEB(b2, (size_t)(T + 2) * 32);
        COMPUTE(aE0, aE1, aE2, aE3, b0);
        // odd step T+1: compute aO/b1, load A(T+2) into aE, stage B(T+3)->b0
        LOADA(aE0, aE1, aE2, aE3, (size_t)(T + 2) * 32);
        WAIT5(); BAR();
        STAGEB(b0, (size_t)(T + 3) * 32);
        COMPUTE(aO0, aO1, aO2, aO3, b1);
        // rotate buffers: (b0,b1,b2) <- (b2,b0,b1)
        ushort_t* tmp_ = b0; b0 = b2; b2 = b1; b1 = tmp_;
    }
    // peeled tail: T=30, 31
    LOADA(aO0, aO1, aO2, aO3, 31 * 32);
    WAIT5(); BAR();
    COMPUTE(aE0, aE1, aE2, aE3, b0);
    WAIT0(); BAR();
    COMPUTE(aO0, aO1, aO2, aO3, b1);

    // epilogue: bias + activation mixture
    #pragma unroll
    for (int ni = 0; ni < 4; ++ni) {
        int col = bcol + wcn + ni * 16 + fr;
        #pragma unroll
        for (int mi = 0; mi < 2; ++mi) {
            int row = brow + wr + mi * 16 + (lane >> 4) * 4;
            #pragma unroll
            for (int r = 0; r < 4; ++r) {
                float v = acc[mi][ni][r] + bias[ni];
                out[(size_t)(row + r) * 1024 + col] = as0 * v + as1 * fmaxf(v, 0.f);
            }
        }
    }
#undef LOADA
#undef STAGEB
#undef COMPUTE
#undef WAIT5
#undef WAIT0
#undef BAR
}

// ---------------- fallback (only if workspace too small): naive fp32 ----------------
__global__ __launch_bounds__(256) void naive_kernel(const float* __restrict__ x,
                                                    const float* __restrict__ Wseed,
                                                    const float* __restrict__ bseed,
                                                    const float* __restrict__ Wsig,
                                                    const float* __restrict__ bsig,
                                                    const float* __restrict__ asig,
                                                    float* __restrict__ out) {
    int idx = blockIdx.x * 256 + threadIdx.x;
    int b = idx >> 10, o = idx & 1023;
    float ws0, ws1, bs0, bs1, as0, as1;
    softmax2(Wsig, ws0, ws1);
    softmax2(bsig, bs0, bs1);
    softmax2(asig, as0, as1);
    float s = 0.f;
    const float* xr = x + (size_t)b * 1024;
    for (int k = 0; k < 1024; ++k) {
        float wc = ws0 * Wseed[((size_t)k << 10) + o] + ws1 * toep_val(Wseed, k, o);
        s += xr[k] * wc;
    }
    float v = s + bs0 * bseed[o];
    out[idx] = as0 * v + as1 * fmaxf(v, 0.f);
}

extern "C" void kernel_launch(void* const* d_in, const int* in_sizes, int n_in,
                              void* d_out, int out_size, void* d_ws, size_t ws_size,
                              hipStream_t stream) {
    const float* x     = (const float*)d_in[0];
    const float* Wseed = (const float*)d_in[1];
    const float* bseed = (const float*)d_in[2];
    const float* Wsig  = (const float*)d_in[3];
    const float* bsig  = (const float*)d_in[4];
    const float* Asig  = (const float*)d_in[5];
    float* out = (float*)d_out;

    const size_t need = (2u << 20) + 1024;
    if (ws_size < need) {
        naive_kernel<<<dim3(8192 * 1024 / 256), dim3(256), 0, stream>>>(
            x, Wseed, bseed, Wsig, bsig, Asig, out);
        return;
    }

    ushort_t* Wt = (ushort_t*)d_ws;   // 2 MB: W_core^T bf16 [1024][1024]

    prep_w_kernel<<<dim3(256), dim3(256), 0, stream>>>(Wseed, Wsig, Wt);
    gemm_kernel<<<dim3(512), dim3(512), 0, stream>>>(x, Wt, bseed, bsig, Asig, out);
}

// Round 15
// 37.487 us; speedup vs baseline: 2.1083x; 2.1083x over previous
//
#include <hip/hip_runtime.h>

typedef unsigned short ushort_t;
typedef __bf16 bf16x8 __attribute__((ext_vector_type(8)));
typedef float f32x4 __attribute__((ext_vector_type(4)));

#define AS1 __attribute__((address_space(1)))
#define AS3 __attribute__((address_space(3)))

__device__ __forceinline__ ushort_t f2bf(float f) {
    unsigned u = __builtin_bit_cast(unsigned, f);
    u = (u + 0x7fffu + ((u >> 16) & 1u)) >> 16;
    return (ushort_t)u;
}

__device__ __forceinline__ void async16(void* lds, const void* g) {
    __builtin_amdgcn_global_load_lds((const AS1 unsigned int*)g,
                                     (AS3 unsigned int*)lds, 16, 0, 0);
}

__device__ __forceinline__ void softmax2(const float* __restrict__ sig, float& s0, float& s1) {
    float a = sig[0], b = sig[1];
    float m = fmaxf(a, b);
    float e0 = __expf(a - m), e1 = __expf(b - m);
    float inv = 1.0f / (e0 + e1);
    s0 = e0 * inv; s1 = e1 * inv;
}

// toeplitz value: W_toep[k][o]
__device__ __forceinline__ float toep_val(const float* __restrict__ Wseed, int k, int o) {
    return (k >= o) ? Wseed[(size_t)(k - o) << 10] : Wseed[o - k];
}

// ---------------- prep: W_core^T bf16 (x consumed fp32 by GEMM) ----------------
__global__ __launch_bounds__(256) void prep_w_kernel(const float* __restrict__ Wseed,
                                                     const float* __restrict__ Wsig,
                                                     ushort_t* __restrict__ Wt) {
    __shared__ float T[64][65];
    int bb = blockIdx.x;                        // 0..255
    int k0 = (bb >> 4) * 64;
    int o0 = (bb & 15) * 64;
    int t = threadIdx.x;
    #pragma unroll
    for (int i = 0; i < 4; ++i) {
        int lin = t + i * 256;
        int kr = lin >> 4;
        int c4 = lin & 15;
        float4 v = *(const float4*)&Wseed[(size_t)(k0 + kr) * 1024 + o0 + c4 * 4];
        T[kr][c4 * 4 + 0] = v.x;
        T[kr][c4 * 4 + 1] = v.y;
        T[kr][c4 * 4 + 2] = v.z;
        T[kr][c4 * 4 + 3] = v.w;
    }
    __syncthreads();
    float s0, s1; softmax2(Wsig, s0, s1);
    #pragma unroll
    for (int i = 0; i < 2; ++i) {
        int lin = t + i * 256;
        int oo = lin >> 3;
        int kq = (lin & 7) * 8;
        unsigned r[4];
        #pragma unroll
        for (int q = 0; q < 4; ++q) {
            float v0 = s0 * T[kq + 2 * q + 0][oo] + s1 * toep_val(Wseed, k0 + kq + 2 * q + 0, o0 + oo);
            float v1 = s0 * T[kq + 2 * q + 1][oo] + s1 * toep_val(Wseed, k0 + kq + 2 * q + 1, o0 + oo);
            r[q] = (unsigned)f2bf(v0) | ((unsigned)f2bf(v1) << 16);
        }
        *(uint4*)&Wt[(size_t)(o0 + oo) * 1024 + k0 + kq] = make_uint4(r[0], r[1], r[2], r[3]);
    }
}

// ---------------- main GEMM: R12 structure (best measured) + corrected B-swizzle --
// 128x128 tile, BK=32, 512 threads = 8 waves (4Mx2N), grid 512 = 2 blocks/CU.
// A: fp32 x staged via async16, chunk ^= row&7 (bank-verified 2-way, free).
// B: bf16 Wt staged via async16, chunk ^= (row>>1)&3 (64B rows: parity x chunk
//    tiles all 8 four-bank spans, 2 lanes/span — R12's row&3 aliased with parity).
// One vmcnt(0)+lgkmcnt(0)+barrier per K-step (2-phase dbuf).
#define BM 128
#define BN 128
#define BK 32
#define NKT 32   // 1024 / 32

__global__ __launch_bounds__(512, 2) void gemm_kernel(const float* __restrict__ Xf,
                                                      const ushort_t* __restrict__ Wt,
                                                      const float* __restrict__ bseed,
                                                      const float* __restrict__ bsig,
                                                      const float* __restrict__ asig,
                                                      float* __restrict__ out) {
    // dbuf x (A 16KB fp32 + B 8KB bf16) = 48 KB
    __shared__ ushort_t lds[24576];
    ushort_t* At0 = lds;            // 8192 ushorts = 16KB (128 rows x 32 fp32)
    ushort_t* Bt0 = lds + 8192;     // 4096 ushorts = 8KB  (128 rows x 32 bf16)
    ushort_t* At1 = lds + 12288;
    ushort_t* Bt1 = lds + 20480;

    const int t = threadIdx.x;        // 0..511
    const int wv = t >> 6;            // 0..7
    const int lane = t & 63;

    // XCD-aware swizzle (512 blocks, bijective)
    const int orig = blockIdx.x;
    const int g = orig & 7;
    const int within = orig >> 3;           // 0..63
    const int rb = g * 8 + (within >> 3);   // row-block 0..63
    const int cb = within & 7;              // col-block 0..7
    const int brow = rb * BM;
    const int bcol = cb * BN;

    // ---- A staging map: 8 threads per 128B row (rows 0..63 per call) ----
    const int ra = t >> 3;                        // 0..63
    const int ca = (t & 7) ^ (ra & 7);            // inverse-swizzled 16B chunk
    const float* gAsw = Xf + (size_t)(brow + ra) * 1024 + 4 * ca;

    // ---- B staging map: 4 threads per 64B row; chunk ^ (row>>1)&3 (corrected) ----
    const int rbb = t >> 2;                       // 0..127
    const int cbk = (t & 3) ^ ((rbb >> 1) & 3);   // inverse-swizzled 16B chunk
    const ushort_t* gBsw = Wt + (size_t)(bcol + rbb) * 1024 + 8 * cbk;

    f32x4 acc[2][4];
    #pragma unroll
    for (int i = 0; i < 2; ++i)
        #pragma unroll
        for (int j = 0; j < 4; ++j) acc[i][j] = (f32x4){0.f, 0.f, 0.f, 0.f};

    // wave decomposition: 4 M-groups x 2 N-groups; wave = 32 rows x 64 cols
    const int wr = (wv >> 1) * 32;     // 0,32,64,96
    const int wcn = (wv & 1) * 64;     // 0,64
    const int fr = lane & 15;
    const int kg = (lane >> 4) * 8;    // k-offset (elements)
    const int c0 = (lane >> 4) * 2;    // A 16B-chunk base

    // epilogue scalars precomputed + pinned
    float bs0, bs1, as0, as1;
    softmax2(bsig, bs0, bs1);
    softmax2(asig, as0, as1);
    float bias[4];
    #pragma unroll
    for (int ni = 0; ni < 4; ++ni)
        bias[ni] = bs0 * bseed[bcol + wcn + ni * 16 + fr];
    asm volatile("" :: "v"(bias[0]), "v"(bias[1]), "v"(bias[2]), "v"(bias[3]),
                       "v"(as0), "v"(as1));
    asm volatile("" ::: "memory");

// A: 2 calls x 8KB (512 threads x 16B); dest linear (byte = t*16 = row*128 + chunk*16)
#define STAGEA(Abuf, ko)                                           \
    do {                                                           \
        async16((Abuf) + wv * 512,        gAsw + (ko));            \
        async16((Abuf) + 4096 + wv * 512, gAsw + 65536 + (ko));    \
    } while (0)

// B: 1 call x 8KB; dest linear (byte = t*16 = row*64 + chunk*16)
#define STAGEB(Bbuf, ko)                                   \
    do {                                                   \
        async16((Bbuf) + wv * 512, gBsw + (ko));           \
    } while (0)

#define COMPUTE(Abuf, Bbuf)                                                        \
    do {                                                                           \
        const float* Af_ = (const float*)(Abuf);                                   \
        bf16x8 af[2], bf[4];                                                       \
        _Pragma("unroll")                                                          \
        for (int mi = 0; mi < 2; ++mi) {                                           \
            int row_ = wr + mi * 16 + fr;                                          \
            f32x4 lo_ = *(const f32x4*)&Af_[row_ * 32 + (((c0)     ^ (row_ & 7)) << 2)]; \
            f32x4 hi_ = *(const f32x4*)&Af_[row_ * 32 + (((c0 + 1) ^ (row_ & 7)) << 2)]; \
            bf16x8 a_;                                                             \
            _Pragma("unroll")                                                      \
            for (int j_ = 0; j_ < 4; ++j_) {                                       \
                a_[j_]     = (__bf16)lo_[j_];                                      \
                a_[4 + j_] = (__bf16)hi_[j_];                                      \
            }                                                                      \
            af[mi] = a_;                                                           \
        }                                                                          \
        _Pragma("unroll")                                                          \
        for (int ni = 0; ni < 4; ++ni) {                                           \
            int rb_ = wcn + ni * 16 + fr;                                          \
            int ch_ = ((kg >> 3) ^ ((rb_ >> 1) & 3)) << 3;                         \
            bf[ni] = *(const bf16x8*)&(Bbuf)[rb_ * 32 + ch_];                      \
        }                                                                          \
        _Pragma("unroll")                                                          \
        for (int mi = 0; mi < 2; ++mi)                                             \
            _Pragma("unroll")                                                      \
            for (int ni = 0; ni < 4; ++ni)                                         \
                acc[mi][ni] = __builtin_amdgcn_mfma_f32_16x16x32_bf16(             \
                    af[mi], bf[ni], acc[mi][ni], 0, 0, 0);                         \
    } while (0)

#define SYNC() do { asm volatile("s_waitcnt vmcnt(0) lgkmcnt(0)" ::: "memory");    \
                    __builtin_amdgcn_s_barrier(); } while (0)

    // prologue: K-step 0 into buf0
    STAGEA(At0, 0);
    STAGEB(Bt0, 0);
    SYNC();
    // main: 15 double-iterations
    for (int it = 0; it < 15; ++it) {
        STAGEA(At1, (2 * it + 1) * BK);       // next tile in flight across compute
        STAGEB(Bt1, (2 * it + 1) * BK);
        COMPUTE(At0, Bt0);
        SYNC();
        STAGEA(At0, (2 * it + 2) * BK);
        STAGEB(Bt0, (2 * it + 2) * BK);
        COMPUTE(At1, Bt1);
        SYNC();
    }
    // tail: K-steps 30, 31
    STAGEA(At1, 31 * BK);
    STAGEB(Bt1, 31 * BK);
    COMPUTE(At0, Bt0);
    SYNC();
    COMPUTE(At1, Bt1);

    // epilogue: bias + activation mixture
    #pragma unroll
    for (int ni = 0; ni < 4; ++ni) {
        int col = bcol + wcn + ni * 16 + fr;
        #pragma unroll
        for (int mi = 0; mi < 2; ++mi) {
            int row = brow + wr + mi * 16 + (lane >> 4) * 4;
            #pragma unroll
            for (int r = 0; r < 4; ++r) {
                float v = acc[mi][ni][r] + bias[ni];
                out[(size_t)(row + r) * 1024 + col] = as0 * v + as1 * fmaxf(v, 0.f);
            }
        }
    }
#undef STAGEA
#undef STAGEB
#undef COMPUTE
#undef SYNC
}

// ---------------- fallback (only if workspace too small): naive fp32 ----------------
__global__ __launch_bounds__(256) void naive_kernel(const float* __restrict__ x,
                                                    const float* __restrict__ Wseed,
                                                    const float* __restrict__ bseed,
                                                    const float* __restrict__ Wsig,
                                                    const float* __restrict__ bsig,
                                                    const float* __restrict__ asig,
                                                    float* __restrict__ out) {
    int idx = blockIdx.x * 256 + threadIdx.x;
    int b = idx >> 10, o = idx & 1023;
    float ws0, ws1, bs0, bs1, as0, as1;
    softmax2(Wsig, ws0, ws1);
    softmax2(bsig, bs0, bs1);
    softmax2(asig, as0, as1);
    float s = 0.f;
    const float* xr = x + (size_t)b * 1024;
    for (int k = 0; k < 1024; ++k) {
        float wc = ws0 * Wseed[((size_t)k << 10) + o] + ws1 * toep_val(Wseed, k, o);
        s += xr[k] * wc;
    }
    float v = s + bs0 * bseed[o];
    out[idx] = as0 * v + as1 * fmaxf(v, 0.f);
}

extern "C" void kernel_launch(void* const* d_in, const int* in_sizes, int n_in,
                              void* d_out, int out_size, void* d_ws, size_t ws_size,
                              hipStream_t stream) {
    const float* x     = (const float*)d_in[0];
    const float* Wseed = (const float*)d_in[1];
    const float* bseed = (const float*)d_in[2];
    const float* Wsig  = (const float*)d_in[3];
    const float* bsig  = (const float*)d_in[4];
    const float* Asig  = (const float*)d_in[5];
    float* out = (float*)d_out;

    const size_t need = (2u << 20) + 1024;
    if (ws_size < need) {
        naive_kernel<<<dim3(8192 * 1024 / 256), dim3(256), 0, stream>>>(
            x, Wseed, bseed, Wsig, bsig, Asig, out);
        return;
    }

    ushort_t* Wt = (ushort_t*)d_ws;   // 2 MB: W_core^T bf16 [1024][1024]

    prep_w_kernel<<<dim3(256), dim3(256), 0, stream>>>(Wseed, Wsig, Wt);
    gemm_kernel<<<dim3(512), dim3(512), 0, stream>>>(x, Wt, bseed, bsig, Asig, out);
}